// Round 17
// baseline (1012.994 us; speedup 1.0000x reference)
//
#include <hip/hip_runtime.h>
#include <hip/hip_bf16.h>

#define T_TOKENS 16384
#define HID 1024
#define NEXP 8
#define INTER 3584
#define PAIRS (2*T_TOKENS)
#define PAD_MAX (PAIRS + NEXP*256)   // 34816, multiple of 256

using f32x4    = __attribute__((ext_vector_type(4))) float;
using bfrag    = __attribute__((ext_vector_type(8))) short;
using float4_t = __attribute__((ext_vector_type(4))) float;
using ushort8_t = __attribute__((ext_vector_type(8))) unsigned short;

__device__ inline unsigned short f2bf(float f){
    unsigned u = __float_as_uint(f);
    u += 0x7FFFu + ((u >> 16) & 1u);          // RNE
    return (unsigned short)(u >> 16);
}

// async global -> LDS, 16B per lane, dest = wave-uniform base + lane*16
__device__ inline void gload16(const unsigned short* g, unsigned short* l){
    __builtin_amdgcn_global_load_lds(
        (const __attribute__((address_space(1))) void*)g,
        (__attribute__((address_space(3))) void*)l, 16, 0, 0);
}

#define BAR_VM8() asm volatile("s_waitcnt vmcnt(8)\n\ts_barrier" ::: "memory")
#define BAR_VM0() asm volatile("s_waitcnt vmcnt(0)\n\ts_barrier" ::: "memory")
#define BAR_PLAIN() asm volatile("s_barrier" ::: "memory")

// bijective XCD swizzle (m204)
__device__ inline int xcd_swz(int flat, int nwg){
    int q = nwg >> 3, r = nwg & 7;
    int xcd = flat & 7, idx = flat >> 3;
    return (xcd < r ? xcd*(q+1) : r*(q+1) + (xcd - r)*q) + idx;
}

// supertile decode: contiguous sw chunk keeps STM M-tiles L2-resident across panels
__device__ inline void st_decode(int sw, int nM, int nP, int STM,
                                 int& mt, int& p){
    int stSize = STM * nP;
    int st = sw / stSize;
    int rem = sw - st * stSize;
    int base = st * STM;
    int stM = (base + STM <= nM) ? STM : (nM - base);
    p  = rem / stM;
    mt = base + (rem - p * stM);
}

// ---------------- f32 -> bf16 conversion for the 3 weight tensors ----------------
__global__ __launch_bounds__(256) void conv3_kernel(
    const float* __restrict__ w1, const float* __restrict__ w3,
    const float* __restrict__ w2,
    unsigned short* __restrict__ w1b, unsigned short* __restrict__ w3b,
    unsigned short* __restrict__ w2b)
{
    const int n = NEXP * INTER * HID;
    const float* in = (blockIdx.y == 0) ? w1 : (blockIdx.y == 1) ? w3 : w2;
    unsigned short* out = (blockIdx.y == 0) ? w1b : (blockIdx.y == 1) ? w3b : w2b;
    int i0 = (blockIdx.x * 256 + threadIdx.x) * 8;
    int stride = gridDim.x * 256 * 8;
    for (int i = i0; i < n; i += stride){
        float4_t a = *reinterpret_cast<const float4_t*>(in + i);
        float4_t b = *reinterpret_cast<const float4_t*>(in + i + 4);
        ushort8_t o;
        o[0]=f2bf(a.x); o[1]=f2bf(a.y); o[2]=f2bf(a.z); o[3]=f2bf(a.w);
        o[4]=f2bf(b.x); o[5]=f2bf(b.y); o[6]=f2bf(b.z); o[7]=f2bf(b.w);
        *reinterpret_cast<ushort8_t*>(out + i) = o;
    }
}

// ---------------- router (+ fused x->bf16 conversion) ----------------
__global__ __launch_bounds__(256) void router_kernel(
    const float* __restrict__ x, const float* __restrict__ gw,
    int* __restrict__ topk_idx, float* __restrict__ topk_w,
    unsigned short* __restrict__ xb)
{
    int wave = threadIdx.x >> 6;
    int lane = threadIdx.x & 63;
    int t = blockIdx.x * 4 + wave;

    float acc[NEXP];
#pragma unroll
    for (int e = 0; e < NEXP; ++e) acc[e] = 0.f;

    const float* xr = x + (size_t)t * HID;
    for (int hb = 0; hb < HID; hb += 64){
        float xv = xr[hb + lane];
#pragma unroll
        for (int e = 0; e < NEXP; ++e)
            acc[e] += xv * gw[e * HID + hb + lane];
    }

    unsigned short* xbr = xb + (size_t)t * HID;
#pragma unroll
    for (int r = 0; r < 2; ++r){
        int c = (lane + r*64) * 8;
        float4_t va = *reinterpret_cast<const float4_t*>(xr + c);
        float4_t vb = *reinterpret_cast<const float4_t*>(xr + c + 4);
        ushort8_t o;
        o[0]=f2bf(va.x); o[1]=f2bf(va.y); o[2]=f2bf(va.z); o[3]=f2bf(va.w);
        o[4]=f2bf(vb.x); o[5]=f2bf(vb.y); o[6]=f2bf(vb.z); o[7]=f2bf(vb.w);
        *reinterpret_cast<ushort8_t*>(xbr + c) = o;
    }

#pragma unroll
    for (int e = 0; e < NEXP; ++e){
#pragma unroll
        for (int s = 32; s > 0; s >>= 1)
            acc[e] += __shfl_xor(acc[e], s, 64);
    }
    if (lane == 0){
        int e0 = 0; float m0 = acc[0];
#pragma unroll
        for (int e = 1; e < NEXP; ++e) if (acc[e] > m0){ m0 = acc[e]; e0 = e; }
        int e1 = -1; float m1 = -1e30f;
#pragma unroll
        for (int e = 0; e < NEXP; ++e) if (e != e0 && acc[e] > m1){ m1 = acc[e]; e1 = e; }
        float p1 = __expf(m1 - m0);
        float inv = 1.f / (1.f + p1);
        topk_idx[2*t]   = e0;
        topk_idx[2*t+1] = e1;
        topk_w[2*t]   = inv;
        topk_w[2*t+1] = p1 * inv;
    }
}

// ---------------- histogram ----------------
__global__ __launch_bounds__(256) void hist_kernel(
    const int* __restrict__ topk_idx, int* __restrict__ counts)
{
    __shared__ int h[NEXP];
    if (threadIdx.x < NEXP) h[threadIdx.x] = 0;
    __syncthreads();
    int i0 = blockIdx.x * 256 + threadIdx.x;
    for (int i = i0; i < PAIRS; i += gridDim.x * 256)
        atomicAdd(&h[topk_idx[i]], 1);
    __syncthreads();
    if (threadIdx.x < NEXP) atomicAdd(&counts[threadIdx.x], h[threadIdx.x]);
}

// prefix scan with 256-row padding (gemm_act uses 256-row M-tiles)
__global__ void scan_kernel(const int* __restrict__ counts, int* __restrict__ offp)
{
    if (threadIdx.x == 0 && blockIdx.x == 0){
        int s = 0;
        for (int e = 0; e < NEXP; ++e){
            offp[e] = s;
            s += (counts[e] + 255) & ~255;
        }
        offp[NEXP] = s;
    }
}

__global__ __launch_bounds__(128) void padfill_kernel(
    const int* __restrict__ counts, const int* __restrict__ offp,
    int* __restrict__ pair_token, float* __restrict__ pair_w)
{
    int e = blockIdx.x;
    int base = offp[e];
    int aligned = offp[e+1] - base;
    for (int s = counts[e] + threadIdx.x; s < aligned; s += 128){
        pair_token[base + s] = (base + s) & (T_TOKENS - 1);
        pair_w[base + s] = 0.f;
    }
}

// ---------------- scatter: block-batched range reservation ----------------
__global__ __launch_bounds__(256) void scatter_kernel(
    const int* __restrict__ topk_idx, const float* __restrict__ topk_w,
    const int* __restrict__ offp, int* __restrict__ cursors,
    int* __restrict__ pair_token, float* __restrict__ pair_w)
{
    __shared__ int hist[NEXP], base[NEXP], lcur[NEXP];
    int tid = threadIdx.x;
    if (tid < NEXP){ hist[tid] = 0; lcur[tid] = 0; }
    __syncthreads();

    int t = blockIdx.x * 256 + tid;
    int e0 = topk_idx[2*t], e1 = topk_idx[2*t + 1];
    atomicAdd(&hist[e0], 1);
    atomicAdd(&hist[e1], 1);
    __syncthreads();

    if (tid < NEXP) base[tid] = atomicAdd(&cursors[tid], hist[tid]);
    __syncthreads();

    int r0 = atomicAdd(&lcur[e0], 1);
    int r1 = atomicAdd(&lcur[e1], 1);
    int p0 = offp[e0] + base[e0] + r0;
    int p1 = offp[e1] + base[e1] + r1;
    pair_token[p0] = t;  pair_w[p0] = topk_w[2*t];
    pair_token[p1] = t;  pair_w[p1] = topk_w[2*t + 1];
}

// ---------------- fused w1/w3 GEMM + SwiGLU: BM256 x 128 icols (h&u), 8 waves ----------------
// Same data-flow as round-15 (375 B/MFMA, zero re-reads) but with the minimal
// barrier set: per K-tile only (a) one barrier after the buffer's last ds_read
// (separating it from stageAll's overwrite-issue) and (b) the vmcnt(8) barrier
// gating the next tile. Intra-tile MFMA needs no barriers (reads complete via
// lgkmcnt before use; no LDS writes between them) -> waves can slide and
// self-overlap (m114) instead of stalling in lockstep 8x per tile.
__global__ __launch_bounds__(512) void gemm_act_kernel(
    const unsigned short* __restrict__ xb,
    const unsigned short* __restrict__ w1b,
    const unsigned short* __restrict__ w3b,
    const int* __restrict__ offp,
    const int* __restrict__ pair_token, const float* __restrict__ pair_w,
    unsigned short* __restrict__ act, int r0)
{
    int nP = gridDim.x, nM = gridDim.y;
    int sw = xcd_swz(blockIdx.y * nP + blockIdx.x, nP * nM);
    int mt, p;
    st_decode(sw, nM, nP, 4, mt, p);
    int by = mt, bx = p;

    int R = r0 + by * 256;
    if (R >= offp[NEXP]) return;
    int e = 0;
    while (offp[e+1] <= R) ++e;
    int icol0 = bx * 128;

    __shared__ alignas(16) unsigned short A0[256*64], A1[256*64];
    __shared__ alignas(16) unsigned short B10[128*64], B11[128*64];
    __shared__ alignas(16) unsigned short B30[128*64], B31[128*64];
    __shared__ int   toks[256];
    __shared__ float pws[256];

    int tid = threadIdx.x;
    if (tid < 256){
        toks[tid] = pair_token[R + tid];
        pws[tid]  = pair_w[R + tid];
    }
    __syncthreads();

    int w = tid >> 6, lane = tid & 63;
    int wm = w >> 2, wn = w & 3;            // 2M x 4N
    int l15 = lane & 15;
    int sr = tid >> 3;                       // staging row 0..63
    int swzc8 = ((tid & 7) ^ (sr & 7)) * 8;  // pre-swizzled source chunk (shorts)

    const unsigned short* w1e = w1b + (size_t)e * INTER * HID;
    const unsigned short* w3e = w3b + (size_t)e * INTER * HID;

    size_t asrc[4];
#pragma unroll
    for (int g = 0; g < 4; ++g)
        asrc[g] = (size_t)toks[g*64 + sr] * HID + swzc8;
    size_t bsrc[2];
#pragma unroll
    for (int g = 0; g < 2; ++g)
        bsrc[g] = (size_t)(icol0 + g*64 + sr) * HID + swzc8;

    int ccol[2];
#pragma unroll
    for (int kk = 0; kk < 2; ++kk)
        ccol[kk] = (((kk*4 + (lane >> 4)) ^ (lane & 7)) * 8);

    f32x4 acc[8][4];   // [m 0..7][ s*2 + nf ]
#pragma unroll
    for (int m = 0; m < 8; ++m)
#pragma unroll
        for (int n = 0; n < 4; ++n)
            acc[m][n] = (f32x4){0.f,0.f,0.f,0.f};

    bfrag a[4][2];
    bfrag bh[2][2], bu[2][2];

    auto stageAll = [&](unsigned short* A, unsigned short* B1, unsigned short* B3, int t){
        int k0 = t * 64;
        gload16(xb  + asrc[0] + k0, A + tid*8);
        gload16(xb  + asrc[1] + k0, A + 4096 + tid*8);
        gload16(xb  + asrc[2] + k0, A + 8192 + tid*8);
        gload16(xb  + asrc[3] + k0, A + 12288 + tid*8);
        gload16(w1e + bsrc[0] + k0, B1 + tid*8);
        gload16(w1e + bsrc[1] + k0, B1 + 4096 + tid*8);
        gload16(w3e + bsrc[0] + k0, B3 + tid*8);
        gload16(w3e + bsrc[1] + k0, B3 + 4096 + tid*8);
    };

    auto dsA = [&](const unsigned short* A, int q){
#pragma unroll
        for (int i = 0; i < 4; ++i)
#pragma unroll
            for (int kk = 0; kk < 2; ++kk)
                a[i][kk] = *reinterpret_cast<const bfrag*>(
                    &A[(wm*128 + q*64 + i*16 + l15)*64 + ccol[kk]]);
    };
    auto dsBh = [&](const unsigned short* B1){
#pragma unroll
        for (int nf = 0; nf < 2; ++nf)
#pragma unroll
            for (int kk = 0; kk < 2; ++kk)
                bh[nf][kk] = *reinterpret_cast<const bfrag*>(
                    &B1[(wn*32 + nf*16 + l15)*64 + ccol[kk]]);
    };
    auto dsBu = [&](const unsigned short* B3){
#pragma unroll
        for (int nf = 0; nf < 2; ++nf)
#pragma unroll
            for (int kk = 0; kk < 2; ++kk)
                bu[nf][kk] = *reinterpret_cast<const bfrag*>(
                    &B3[(wn*32 + nf*16 + l15)*64 + ccol[kk]]);
    };
    auto mma = [&](int q, int s){
        if (s == 0){
#pragma unroll
            for (int kk = 0; kk < 2; ++kk)
#pragma unroll
                for (int nf = 0; nf < 2; ++nf)
#pragma unroll
                    for (int i = 0; i < 4; ++i)
                        acc[q*4+i][nf] = __builtin_amdgcn_mfma_f32_16x16x32_bf16(
                            a[i][kk], bh[nf][kk], acc[q*4+i][nf], 0, 0, 0);
        } else {
#pragma unroll
            for (int kk = 0; kk < 2; ++kk)
#pragma unroll
                for (int nf = 0; nf < 2; ++nf)
#pragma unroll
                    for (int i = 0; i < 4; ++i)
                        acc[q*4+i][2+nf] = __builtin_amdgcn_mfma_f32_16x16x32_bf16(
                            a[i][kk], bu[nf][kk], acc[q*4+i][2+nf], 0, 0, 0);
        }
    };

    // mode 0: steady (issue t+2 after last-read barrier, vmcnt8 gate);
    // mode 1: drain (vmcnt0); mode 2: last (no waits beyond reads)
    auto TILE = [&](const unsigned short* A, const unsigned short* B1, const unsigned short* B3,
                    unsigned short* Aw, unsigned short* B1w, unsigned short* B3w,
                    int tn, int mode){
        __builtin_amdgcn_s_setprio(1);
        dsA(A, 0); dsBh(B1); dsBu(B3);      // q0 frags + both B streams
        mma(0, 0); mma(0, 1);
        dsA(A, 1);                           // q1 frags (last buf read)
        mma(1, 1);
        __builtin_amdgcn_s_setprio(0);
        BAR_PLAIN();                         // all waves' buf reads complete
        if (mode == 0){ stageAll(Aw, B1w, B3w, tn); BAR_VM8(); }
        else if (mode == 1){ BAR_VM0(); }
        __builtin_amdgcn_s_setprio(1);
        mma(1, 0);                           // register-only tail
        __builtin_amdgcn_s_setprio(0);
    };

    const int NT = HID / 64;   // 16 (even)
    stageAll(A0, B10, B30, 0);
    stageAll(A1, B11, B31, 1);
    BAR_VM8();   // tile0 landed; tile1's 8 in flight

#pragma unroll 1
    for (int t = 0; t < NT - 2; t += 2){
        TILE(A0, B10, B30, A0, B10, B30, t + 2, 0);
        TILE(A1, B11, B31, A1, B11, B31, t + 3, 0);
    }
    TILE(A0, B10, B30, A0, B10, B30, 0, 1);   // t=NT-2: drain tile NT-1
    TILE(A1, B11, B31, A1, B11, B31, 0, 2);   // t=NT-1

    // epilogue: act = pair_w * silu(h) * u
    size_t arow0 = (size_t)(by * 256) * INTER;
#pragma unroll
    for (int m = 0; m < 8; ++m){
#pragma unroll
        for (int nf = 0; nf < 2; ++nf){
#pragma unroll
            for (int j = 0; j < 4; ++j){
                int rl = wm*128 + m*16 + (lane >> 4)*4 + j;
                float h = acc[m][nf][j];
                float u = acc[m][2 + nf][j];
                float v = pws[rl] * h * u / (1.f + __expf(-h));
                int ic = icol0 + wn*32 + nf*16 + l15;
                act[arow0 + (size_t)rl * INTER + ic] = f2bf(v);
            }
        }
    }
}

// ---------------- down-proj GEMM (round-10 proven 2-phase 128x128, BK=64) ----------------
__global__ __launch_bounds__(256) void gemm2_kernel(
    const unsigned short* __restrict__ act,
    const unsigned short* __restrict__ w2b,
    const int* __restrict__ offp,
    const int* __restrict__ pair_token,
    float* __restrict__ out, int r0)
{
    int nP = gridDim.x, nM = gridDim.y;
    int sw = xcd_swz(blockIdx.y * nP + blockIdx.x, nP * nM);
    int mt, p;
    st_decode(sw, nM, nP, 4, mt, p);
    int by = mt, bx = p;

    int R = r0 + by * 128;
    if (R >= offp[NEXP]) return;
    int e = 0;
    while (offp[e+1] <= R) ++e;
    int h0 = bx * 128;

    __shared__ alignas(16) unsigned short As0[128*64], As1[128*64];
    __shared__ alignas(16) unsigned short Bs0[128*64], Bs1[128*64];
    __shared__ int toks[128];

    int tid = threadIdx.x;
    if (tid < 128) toks[tid] = pair_token[R + tid];
    __syncthreads();

    int w = tid >> 6, lane = tid & 63;
    int wm = w >> 1, wn = w & 1;
    int lr = lane >> 3;
    int l15 = lane & 15;
    int swz8 = ((lane & 7) ^ lr) * 8;

    const unsigned short* w2e = w2b + (size_t)e * HID * INTER;
    size_t arow0 = (size_t)(by * 128) * INTER;

    size_t asrc[4], bsrc[4];
#pragma unroll
    for (int i = 0; i < 4; ++i){
        asrc[i] = arow0 + (size_t)(w*32 + i*8 + lr) * INTER + swz8;
        bsrc[i] = (size_t)(h0 + w*32 + i*8 + lr) * INTER + swz8;
    }

    int ccol[2];
#pragma unroll
    for (int kk = 0; kk < 2; ++kk)
        ccol[kk] = (((kk*4 + (lane >> 4)) ^ (lane & 7)) * 8);

    f32x4 acc[4][4];
#pragma unroll
    for (int m = 0; m < 4; ++m)
#pragma unroll
        for (int n = 0; n < 4; ++n)
            acc[m][n] = (f32x4){0.f,0.f,0.f,0.f};

    auto stageT = [&](unsigned short* As, unsigned short* Bs, int t){
        int kc = t * 64;
#pragma unroll
        for (int i = 0; i < 4; ++i) gload16(act + asrc[i] + kc, As + (w*32 + i*8)*64);
#pragma unroll
        for (int i = 0; i < 4; ++i) gload16(w2e + bsrc[i] + kc, Bs + (w*32 + i*8)*64);
    };

    auto computeT = [&](const unsigned short* As, const unsigned short* Bs){
        __builtin_amdgcn_s_setprio(1);
#pragma unroll
        for (int kk = 0; kk < 2; ++kk){
            int cc = ccol[kk];
            bfrag a[4];
#pragma unroll
            for (int m = 0; m < 4; ++m)
                a[m] = *reinterpret_cast<const bfrag*>(&As[(wm*64 + m*16 + l15)*64 + cc]);
#pragma unroll
            for (int n = 0; n < 4; ++n){
                bfrag b = *reinterpret_cast<const bfrag*>(&Bs[(wn*64 + n*16 + l15)*64 + cc]);
#pragma unroll
                for (int m = 0; m < 4; ++m)
                    acc[m][n] = __builtin_amdgcn_mfma_f32_16x16x32_bf16(a[m], b, acc[m][n], 0, 0, 0);
            }
        }
        __builtin_amdgcn_s_setprio(0);
    };

    const int NT = INTER / 64;   // 56 (even)
    stageT(As0, Bs0, 0);
    stageT(As1, Bs1, 1);
#pragma unroll 1
    for (int t = 0; t < NT - 2; t += 2){
        BAR_VM8();
        computeT(As0, Bs0);
        BAR_PLAIN();
        stageT(As0, Bs0, t + 2);
        BAR_VM8();
        computeT(As1, Bs1);
        BAR_PLAIN();
        stageT(As1, Bs1, t + 3);
    }
    BAR_VM8();
    computeT(As0, Bs0);
    BAR_VM0();
    computeT(As1, Bs1);

#pragma unroll
    for (int m = 0; m < 4; ++m){
#pragma unroll
        for (int n = 0; n < 4; ++n){
#pragma unroll
            for (int j = 0; j < 4; ++j){
                int rl = wm*64 + m*16 + (lane >> 4)*4 + j;
                int hc = h0 + wn*64 + n*16 + l15;
                atomicAdd(&out[(size_t)toks[rl] * HID + hc], acc[m][n][j]);
            }
        }
    }
}

extern "C" void kernel_launch(void* const* d_in, const int* in_sizes, int n_in,
                              void* d_out, int out_size, void* d_ws, size_t ws_size,
                              hipStream_t stream)
{
    const float* x  = (const float*)d_in[0];
    const float* gw = (const float*)d_in[1];
    const float* w1 = (const float*)d_in[2];
    const float* w3 = (const float*)d_in[3];
    const float* w2 = (const float*)d_in[4];
    float* out = (float*)d_out;

    char* ws = (char*)d_ws;
    size_t off = 0;
    auto bump = [&](size_t bytes) -> void* {
        void* p = ws + off;
        off = (off + bytes + 255) & ~(size_t)255;
        return p;
    };
    int*   counts     = (int*)bump(32);
    int*   cursors    = (int*)bump(32);
    int*   offp       = (int*)bump(64);
    int*   topk_idx   = (int*)bump((size_t)PAIRS * 4);
    float* topk_w     = (float*)bump((size_t)PAIRS * 4);
    int*   pair_token = (int*)bump((size_t)PAD_MAX * 4);
    float* pair_w     = (float*)bump((size_t)PAD_MAX * 4);
    unsigned short* xb  = (unsigned short*)bump((size_t)T_TOKENS * HID * 2);
    unsigned short* w1b = (unsigned short*)bump((size_t)NEXP * INTER * HID * 2);
    unsigned short* w3b = (unsigned short*)bump((size_t)NEXP * INTER * HID * 2);
    unsigned short* w2b = (unsigned short*)bump((size_t)NEXP * HID * INTER * 2);
    unsigned short* act = (unsigned short*)(ws + off);

    size_t rem = (ws_size > off) ? (ws_size - off) : 0;
    int RC = (int)(rem / ((size_t)INTER * 2));
    RC &= ~255;
    if (RC > PAD_MAX) RC = PAD_MAX;
    if (RC < 256) RC = 256;
    int nchunks = (PAD_MAX + RC - 1) / RC;

    hipMemsetAsync(d_out, 0, (size_t)T_TOKENS * HID * 4, stream);
    hipMemsetAsync(ws, 0, 1024, stream);

    conv3_kernel<<<dim3(768, 3), 256, 0, stream>>>(w1, w3, w2, w1b, w3b, w2b);

    router_kernel<<<T_TOKENS/4, 256, 0, stream>>>(x, gw, topk_idx, topk_w, xb);
    hist_kernel<<<64, 256, 0, stream>>>(topk_idx, counts);
    scan_kernel<<<1, 64, 0, stream>>>(counts, offp);
    padfill_kernel<<<NEXP, 128, 0, stream>>>(counts, offp, pair_token, pair_w);
    scatter_kernel<<<T_TOKENS/256, 256, 0, stream>>>(topk_idx, topk_w, offp, cursors,
                                                     pair_token, pair_w);

    for (int c = 0; c < nchunks; ++c){
        int r0 = c * RC;
        gemm_act_kernel<<<dim3(INTER/128, RC/256), 512, 0, stream>>>(
            xb, w1b, w3b, offp, pair_token, pair_w, act, r0);
        gemm2_kernel<<<dim3(HID/128, RC/128), 256, 0, stream>>>(
            act, w2b, offp, pair_token, out, r0);
    }
}

// Round 19
// 1001.705 us; speedup vs baseline: 1.0113x; 1.0113x over previous
//
#include <hip/hip_runtime.h>
#include <hip/hip_bf16.h>

#define T_TOKENS 16384
#define HID 1024
#define NEXP 8
#define INTER 3584
#define PAIRS (2*T_TOKENS)
#define PAD_MAX (PAIRS + NEXP*256)   // 34816, multiple of 256

using f32x4    = __attribute__((ext_vector_type(4))) float;
using bfrag    = __attribute__((ext_vector_type(8))) short;
using float4_t = __attribute__((ext_vector_type(4))) float;
using ushort8_t = __attribute__((ext_vector_type(8))) unsigned short;

__device__ inline unsigned short f2bf(float f){
    unsigned u = __float_as_uint(f);
    u += 0x7FFFu + ((u >> 16) & 1u);          // RNE
    return (unsigned short)(u >> 16);
}

// async global -> LDS, 16B per lane, dest = wave-uniform base + lane*16
__device__ inline void gload16(const unsigned short* g, unsigned short* l){
    __builtin_amdgcn_global_load_lds(
        (const __attribute__((address_space(1))) void*)g,
        (__attribute__((address_space(3))) void*)l, 16, 0, 0);
}

#define BAR_VM8() asm volatile("s_waitcnt vmcnt(8)\n\ts_barrier" ::: "memory")
#define BAR_VM0() asm volatile("s_waitcnt vmcnt(0)\n\ts_barrier" ::: "memory")
#define BAR_PLAIN() asm volatile("s_barrier" ::: "memory")
// HW-retire all outstanding DS reads before proceeding (s_barrier does NOT
// drain lgkmcnt; required before any wave may issue LDS overwrites)
#define LGKM0() asm volatile("s_waitcnt lgkmcnt(0)" ::: "memory")

// bijective XCD swizzle (m204)
__device__ inline int xcd_swz(int flat, int nwg){
    int q = nwg >> 3, r = nwg & 7;
    int xcd = flat & 7, idx = flat >> 3;
    return (xcd < r ? xcd*(q+1) : r*(q+1) + (xcd - r)*q) + idx;
}

// supertile decode: contiguous sw chunk keeps STM M-tiles L2-resident across panels
__device__ inline void st_decode(int sw, int nM, int nP, int STM,
                                 int& mt, int& p){
    int stSize = STM * nP;
    int st = sw / stSize;
    int rem = sw - st * stSize;
    int base = st * STM;
    int stM = (base + STM <= nM) ? STM : (nM - base);
    p  = rem / stM;
    mt = base + (rem - p * stM);
}

// ---------------- f32 -> bf16 conversion for the 3 weight tensors ----------------
__global__ __launch_bounds__(256) void conv3_kernel(
    const float* __restrict__ w1, const float* __restrict__ w3,
    const float* __restrict__ w2,
    unsigned short* __restrict__ w1b, unsigned short* __restrict__ w3b,
    unsigned short* __restrict__ w2b)
{
    const int n = NEXP * INTER * HID;
    const float* in = (blockIdx.y == 0) ? w1 : (blockIdx.y == 1) ? w3 : w2;
    unsigned short* out = (blockIdx.y == 0) ? w1b : (blockIdx.y == 1) ? w3b : w2b;
    int i0 = (blockIdx.x * 256 + threadIdx.x) * 8;
    int stride = gridDim.x * 256 * 8;
    for (int i = i0; i < n; i += stride){
        float4_t a = *reinterpret_cast<const float4_t*>(in + i);
        float4_t b = *reinterpret_cast<const float4_t*>(in + i + 4);
        ushort8_t o;
        o[0]=f2bf(a.x); o[1]=f2bf(a.y); o[2]=f2bf(a.z); o[3]=f2bf(a.w);
        o[4]=f2bf(b.x); o[5]=f2bf(b.y); o[6]=f2bf(b.z); o[7]=f2bf(b.w);
        *reinterpret_cast<ushort8_t*>(out + i) = o;
    }
}

// ---------------- router (+ fused x->bf16 conversion) ----------------
__global__ __launch_bounds__(256) void router_kernel(
    const float* __restrict__ x, const float* __restrict__ gw,
    int* __restrict__ topk_idx, float* __restrict__ topk_w,
    unsigned short* __restrict__ xb)
{
    int wave = threadIdx.x >> 6;
    int lane = threadIdx.x & 63;
    int t = blockIdx.x * 4 + wave;

    float acc[NEXP];
#pragma unroll
    for (int e = 0; e < NEXP; ++e) acc[e] = 0.f;

    const float* xr = x + (size_t)t * HID;
    for (int hb = 0; hb < HID; hb += 64){
        float xv = xr[hb + lane];
#pragma unroll
        for (int e = 0; e < NEXP; ++e)
            acc[e] += xv * gw[e * HID + hb + lane];
    }

    unsigned short* xbr = xb + (size_t)t * HID;
#pragma unroll
    for (int r = 0; r < 2; ++r){
        int c = (lane + r*64) * 8;
        float4_t va = *reinterpret_cast<const float4_t*>(xr + c);
        float4_t vb = *reinterpret_cast<const float4_t*>(xr + c + 4);
        ushort8_t o;
        o[0]=f2bf(va.x); o[1]=f2bf(va.y); o[2]=f2bf(va.z); o[3]=f2bf(va.w);
        o[4]=f2bf(vb.x); o[5]=f2bf(vb.y); o[6]=f2bf(vb.z); o[7]=f2bf(vb.w);
        *reinterpret_cast<ushort8_t*>(xbr + c) = o;
    }

#pragma unroll
    for (int e = 0; e < NEXP; ++e){
#pragma unroll
        for (int s = 32; s > 0; s >>= 1)
            acc[e] += __shfl_xor(acc[e], s, 64);
    }
    if (lane == 0){
        int e0 = 0; float m0 = acc[0];
#pragma unroll
        for (int e = 1; e < NEXP; ++e) if (acc[e] > m0){ m0 = acc[e]; e0 = e; }
        int e1 = -1; float m1 = -1e30f;
#pragma unroll
        for (int e = 0; e < NEXP; ++e) if (e != e0 && acc[e] > m1){ m1 = acc[e]; e1 = e; }
        float p1 = __expf(m1 - m0);
        float inv = 1.f / (1.f + p1);
        topk_idx[2*t]   = e0;
        topk_idx[2*t+1] = e1;
        topk_w[2*t]   = inv;
        topk_w[2*t+1] = p1 * inv;
    }
}

// ---------------- histogram ----------------
__global__ __launch_bounds__(256) void hist_kernel(
    const int* __restrict__ topk_idx, int* __restrict__ counts)
{
    __shared__ int h[NEXP];
    if (threadIdx.x < NEXP) h[threadIdx.x] = 0;
    __syncthreads();
    int i0 = blockIdx.x * 256 + threadIdx.x;
    for (int i = i0; i < PAIRS; i += gridDim.x * 256)
        atomicAdd(&h[topk_idx[i]], 1);
    __syncthreads();
    if (threadIdx.x < NEXP) atomicAdd(&counts[threadIdx.x], h[threadIdx.x]);
}

// prefix scan with 256-row padding (gemm_act uses 256-row M-tiles)
__global__ void scan_kernel(const int* __restrict__ counts, int* __restrict__ offp)
{
    if (threadIdx.x == 0 && blockIdx.x == 0){
        int s = 0;
        for (int e = 0; e < NEXP; ++e){
            offp[e] = s;
            s += (counts[e] + 255) & ~255;
        }
        offp[NEXP] = s;
    }
}

__global__ __launch_bounds__(128) void padfill_kernel(
    const int* __restrict__ counts, const int* __restrict__ offp,
    int* __restrict__ pair_token, float* __restrict__ pair_w)
{
    int e = blockIdx.x;
    int base = offp[e];
    int aligned = offp[e+1] - base;
    for (int s = counts[e] + threadIdx.x; s < aligned; s += 128){
        pair_token[base + s] = (base + s) & (T_TOKENS - 1);
        pair_w[base + s] = 0.f;
    }
}

// ---------------- scatter: block-batched range reservation ----------------
__global__ __launch_bounds__(256) void scatter_kernel(
    const int* __restrict__ topk_idx, const float* __restrict__ topk_w,
    const int* __restrict__ offp, int* __restrict__ cursors,
    int* __restrict__ pair_token, float* __restrict__ pair_w)
{
    __shared__ int hist[NEXP], base[NEXP], lcur[NEXP];
    int tid = threadIdx.x;
    if (tid < NEXP){ hist[tid] = 0; lcur[tid] = 0; }
    __syncthreads();

    int t = blockIdx.x * 256 + tid;
    int e0 = topk_idx[2*t], e1 = topk_idx[2*t + 1];
    atomicAdd(&hist[e0], 1);
    atomicAdd(&hist[e1], 1);
    __syncthreads();

    if (tid < NEXP) base[tid] = atomicAdd(&cursors[tid], hist[tid]);
    __syncthreads();

    int r0 = atomicAdd(&lcur[e0], 1);
    int r1 = atomicAdd(&lcur[e1], 1);
    int p0 = offp[e0] + base[e0] + r0;
    int p1 = offp[e1] + base[e1] + r1;
    pair_token[p0] = t;  pair_w[p0] = topk_w[2*t];
    pair_token[p1] = t;  pair_w[p1] = topk_w[2*t + 1];
}

// ---------------- fused w1/w3 GEMM + SwiGLU: BM256 x 128 icols (h&u), 8 waves ----------------
// Round-17 proven: 375 B/MFMA, zero re-reads, minimal barriers (2/tile), register-
// only mma tail overlapping the stage issue. All ds_reads are consumed by MFMAs
// BEFORE the barrier (mma(1,1) uses the last-issued reads -> lgkm FIFO drained),
// so no explicit lgkmcnt needed here. Unchanged from round 17.
__global__ __launch_bounds__(512) void gemm_act_kernel(
    const unsigned short* __restrict__ xb,
    const unsigned short* __restrict__ w1b,
    const unsigned short* __restrict__ w3b,
    const int* __restrict__ offp,
    const int* __restrict__ pair_token, const float* __restrict__ pair_w,
    unsigned short* __restrict__ act, int r0)
{
    int nP = gridDim.x, nM = gridDim.y;
    int sw = xcd_swz(blockIdx.y * nP + blockIdx.x, nP * nM);
    int mt, p;
    st_decode(sw, nM, nP, 4, mt, p);
    int by = mt, bx = p;

    int R = r0 + by * 256;
    if (R >= offp[NEXP]) return;
    int e = 0;
    while (offp[e+1] <= R) ++e;
    int icol0 = bx * 128;

    __shared__ alignas(16) unsigned short A0[256*64], A1[256*64];
    __shared__ alignas(16) unsigned short B10[128*64], B11[128*64];
    __shared__ alignas(16) unsigned short B30[128*64], B31[128*64];
    __shared__ int   toks[256];
    __shared__ float pws[256];

    int tid = threadIdx.x;
    if (tid < 256){
        toks[tid] = pair_token[R + tid];
        pws[tid]  = pair_w[R + tid];
    }
    __syncthreads();

    int w = tid >> 6, lane = tid & 63;
    int wm = w >> 2, wn = w & 3;            // 2M x 4N
    int l15 = lane & 15;
    int sr = tid >> 3;                       // staging row 0..63
    int swzc8 = ((tid & 7) ^ (sr & 7)) * 8;  // pre-swizzled source chunk (shorts)

    const unsigned short* w1e = w1b + (size_t)e * INTER * HID;
    const unsigned short* w3e = w3b + (size_t)e * INTER * HID;

    size_t asrc[4];
#pragma unroll
    for (int g = 0; g < 4; ++g)
        asrc[g] = (size_t)toks[g*64 + sr] * HID + swzc8;
    size_t bsrc[2];
#pragma unroll
    for (int g = 0; g < 2; ++g)
        bsrc[g] = (size_t)(icol0 + g*64 + sr) * HID + swzc8;

    int ccol[2];
#pragma unroll
    for (int kk = 0; kk < 2; ++kk)
        ccol[kk] = (((kk*4 + (lane >> 4)) ^ (lane & 7)) * 8);

    f32x4 acc[8][4];   // [m 0..7][ s*2 + nf ]
#pragma unroll
    for (int m = 0; m < 8; ++m)
#pragma unroll
        for (int n = 0; n < 4; ++n)
            acc[m][n] = (f32x4){0.f,0.f,0.f,0.f};

    bfrag a[4][2];
    bfrag bh[2][2], bu[2][2];

    auto stageAll = [&](unsigned short* A, unsigned short* B1, unsigned short* B3, int t){
        int k0 = t * 64;
        gload16(xb  + asrc[0] + k0, A + tid*8);
        gload16(xb  + asrc[1] + k0, A + 4096 + tid*8);
        gload16(xb  + asrc[2] + k0, A + 8192 + tid*8);
        gload16(xb  + asrc[3] + k0, A + 12288 + tid*8);
        gload16(w1e + bsrc[0] + k0, B1 + tid*8);
        gload16(w1e + bsrc[1] + k0, B1 + 4096 + tid*8);
        gload16(w3e + bsrc[0] + k0, B3 + tid*8);
        gload16(w3e + bsrc[1] + k0, B3 + 4096 + tid*8);
    };

    auto dsA = [&](const unsigned short* A, int q){
#pragma unroll
        for (int i = 0; i < 4; ++i)
#pragma unroll
            for (int kk = 0; kk < 2; ++kk)
                a[i][kk] = *reinterpret_cast<const bfrag*>(
                    &A[(wm*128 + q*64 + i*16 + l15)*64 + ccol[kk]]);
    };
    auto dsBh = [&](const unsigned short* B1){
#pragma unroll
        for (int nf = 0; nf < 2; ++nf)
#pragma unroll
            for (int kk = 0; kk < 2; ++kk)
                bh[nf][kk] = *reinterpret_cast<const bfrag*>(
                    &B1[(wn*32 + nf*16 + l15)*64 + ccol[kk]]);
    };
    auto dsBu = [&](const unsigned short* B3){
#pragma unroll
        for (int nf = 0; nf < 2; ++nf)
#pragma unroll
            for (int kk = 0; kk < 2; ++kk)
                bu[nf][kk] = *reinterpret_cast<const bfrag*>(
                    &B3[(wn*32 + nf*16 + l15)*64 + ccol[kk]]);
    };
    auto mma = [&](int q, int s){
        if (s == 0){
#pragma unroll
            for (int kk = 0; kk < 2; ++kk)
#pragma unroll
                for (int nf = 0; nf < 2; ++nf)
#pragma unroll
                    for (int i = 0; i < 4; ++i)
                        acc[q*4+i][nf] = __builtin_amdgcn_mfma_f32_16x16x32_bf16(
                            a[i][kk], bh[nf][kk], acc[q*4+i][nf], 0, 0, 0);
        } else {
#pragma unroll
            for (int kk = 0; kk < 2; ++kk)
#pragma unroll
                for (int nf = 0; nf < 2; ++nf)
#pragma unroll
                    for (int i = 0; i < 4; ++i)
                        acc[q*4+i][2+nf] = __builtin_amdgcn_mfma_f32_16x16x32_bf16(
                            a[i][kk], bu[nf][kk], acc[q*4+i][2+nf], 0, 0, 0);
        }
    };

    auto TILE = [&](const unsigned short* A, const unsigned short* B1, const unsigned short* B3,
                    unsigned short* Aw, unsigned short* B1w, unsigned short* B3w,
                    int tn, int mode){
        __builtin_amdgcn_s_setprio(1);
        dsA(A, 0); dsBh(B1); dsBu(B3);
        mma(0, 0); mma(0, 1);
        dsA(A, 1);
        mma(1, 1);
        __builtin_amdgcn_s_setprio(0);
        LGKM0();                  // belt-and-braces: all DS reads HW-retired
        BAR_PLAIN();
        if (mode == 0){ stageAll(Aw, B1w, B3w, tn); BAR_VM8(); }
        else if (mode == 1){ BAR_VM0(); }
        __builtin_amdgcn_s_setprio(1);
        mma(1, 0);
        __builtin_amdgcn_s_setprio(0);
    };

    const int NT = HID / 64;   // 16 (even)
    stageAll(A0, B10, B30, 0);
    stageAll(A1, B11, B31, 1);
    BAR_VM8();

#pragma unroll 1
    for (int t = 0; t < NT - 2; t += 2){
        TILE(A0, B10, B30, A0, B10, B30, t + 2, 0);
        TILE(A1, B11, B31, A1, B11, B31, t + 3, 0);
    }
    TILE(A0, B10, B30, A0, B10, B30, 0, 1);
    TILE(A1, B11, B31, A1, B11, B31, 0, 2);

    size_t arow0 = (size_t)(by * 256) * INTER;
#pragma unroll
    for (int m = 0; m < 8; ++m){
#pragma unroll
        for (int nf = 0; nf < 2; ++nf){
#pragma unroll
            for (int j = 0; j < 4; ++j){
                int rl = wm*128 + m*16 + (lane >> 4)*4 + j;
                float h = acc[m][nf][j];
                float u = acc[m][2 + nf][j];
                float v = pws[rl] * h * u / (1.f + __expf(-h));
                int ic = icol0 + wn*32 + nf*16 + l15;
                act[arow0 + (size_t)rl * INTER + ic] = f2bf(v);
            }
        }
    }
}

// ---------------- down-proj GEMM: 2-phase 128x128, R17-style minimal barriers ----------------
// RACE FIX vs round 18: mmaK(0) consumes only the kk=0 frags, so the compiler's
// fine-grained lgkmcnt leaves the 8 kk=1 ds_reads PENDING across s_barrier
// (s_barrier does not drain lgkmcnt) -> they raced with the stage overwrite.
// Explicit lgkmcnt(0) before the barrier retires all 16 reads in hardware.
__global__ __launch_bounds__(256) void gemm2_kernel(
    const unsigned short* __restrict__ act,
    const unsigned short* __restrict__ w2b,
    const int* __restrict__ offp,
    const int* __restrict__ pair_token,
    float* __restrict__ out, int r0)
{
    int nP = gridDim.x, nM = gridDim.y;
    int sw = xcd_swz(blockIdx.y * nP + blockIdx.x, nP * nM);
    int mt, p;
    st_decode(sw, nM, nP, 4, mt, p);
    int by = mt, bx = p;

    int R = r0 + by * 128;
    if (R >= offp[NEXP]) return;
    int e = 0;
    while (offp[e+1] <= R) ++e;
    int h0 = bx * 128;

    __shared__ alignas(16) unsigned short As0[128*64], As1[128*64];
    __shared__ alignas(16) unsigned short Bs0[128*64], Bs1[128*64];
    __shared__ int toks[128];

    int tid = threadIdx.x;
    if (tid < 128) toks[tid] = pair_token[R + tid];
    __syncthreads();

    int w = tid >> 6, lane = tid & 63;
    int wm = w >> 1, wn = w & 1;
    int lr = lane >> 3;
    int l15 = lane & 15;
    int swz8 = ((lane & 7) ^ lr) * 8;

    const unsigned short* w2e = w2b + (size_t)e * HID * INTER;
    size_t arow0 = (size_t)(by * 128) * INTER;

    size_t asrc[4], bsrc[4];
#pragma unroll
    for (int i = 0; i < 4; ++i){
        asrc[i] = arow0 + (size_t)(w*32 + i*8 + lr) * INTER + swz8;
        bsrc[i] = (size_t)(h0 + w*32 + i*8 + lr) * INTER + swz8;
    }

    int ccol[2];
#pragma unroll
    for (int kk = 0; kk < 2; ++kk)
        ccol[kk] = (((kk*4 + (lane >> 4)) ^ (lane & 7)) * 8);

    f32x4 acc[4][4];
#pragma unroll
    for (int m = 0; m < 4; ++m)
#pragma unroll
        for (int n = 0; n < 4; ++n)
            acc[m][n] = (f32x4){0.f,0.f,0.f,0.f};

    bfrag a[4][2], b[4][2];

    auto stageT = [&](unsigned short* As, unsigned short* Bs, int t){
        int kc = t * 64;
#pragma unroll
        for (int i = 0; i < 4; ++i) gload16(act + asrc[i] + kc, As + (w*32 + i*8)*64);
#pragma unroll
        for (int i = 0; i < 4; ++i) gload16(w2e + bsrc[i] + kc, Bs + (w*32 + i*8)*64);
    };

    auto dsAll = [&](const unsigned short* As, const unsigned short* Bs){
#pragma unroll
        for (int kk = 0; kk < 2; ++kk){
            int cc = ccol[kk];
#pragma unroll
            for (int m = 0; m < 4; ++m)
                a[m][kk] = *reinterpret_cast<const bfrag*>(&As[(wm*64 + m*16 + l15)*64 + cc]);
#pragma unroll
            for (int n = 0; n < 4; ++n)
                b[n][kk] = *reinterpret_cast<const bfrag*>(&Bs[(wn*64 + n*16 + l15)*64 + cc]);
        }
    };
    auto mmaK = [&](int kk){
#pragma unroll
        for (int n = 0; n < 4; ++n)
#pragma unroll
            for (int m = 0; m < 4; ++m)
                acc[m][n] = __builtin_amdgcn_mfma_f32_16x16x32_bf16(
                    a[m][kk], b[n][kk], acc[m][n], 0, 0, 0);
    };

    // mode 0: steady; 1: drain next tile (vmcnt0); 2: last (no wait)
    auto TILE = [&](const unsigned short* As, const unsigned short* Bs,
                    unsigned short* Aw, unsigned short* Bw, int tn, int mode){
        __builtin_amdgcn_s_setprio(1);
        dsAll(As, Bs);            // buf's last reads (16 x ds_read_b128)
        mmaK(0);
        __builtin_amdgcn_s_setprio(0);
        LGKM0();                  // retire ALL ds_reads (incl. kk=1) before barrier
        BAR_PLAIN();
        if (mode == 0){ stageT(Aw, Bw, tn); BAR_VM8(); }
        else if (mode == 1){ BAR_VM0(); }
        __builtin_amdgcn_s_setprio(1);
        mmaK(1);                  // register-only, overlaps issued loads
        __builtin_amdgcn_s_setprio(0);
    };

    const int NT = INTER / 64;   // 56 (even)
    stageT(As0, Bs0, 0);
    stageT(As1, Bs1, 1);
    BAR_VM8();

#pragma unroll 1
    for (int t = 0; t < NT - 2; t += 2){
        TILE(As0, Bs0, As0, Bs0, t + 2, 0);
        TILE(As1, Bs1, As1, Bs1, t + 3, 0);
    }
    TILE(As0, Bs0, As0, Bs0, 0, 1);   // t=NT-2: drain tile NT-1
    TILE(As1, Bs1, As1, Bs1, 0, 2);   // t=NT-1

#pragma unroll
    for (int m = 0; m < 4; ++m){
#pragma unroll
        for (int n = 0; n < 4; ++n){
#pragma unroll
            for (int j = 0; j < 4; ++j){
                int rl = wm*64 + m*16 + (lane >> 4)*4 + j;
                int hc = h0 + wn*64 + n*16 + l15;
                atomicAdd(&out[(size_t)toks[rl] * HID + hc], acc[m][n][j]);
            }
        }
    }
}

extern "C" void kernel_launch(void* const* d_in, const int* in_sizes, int n_in,
                              void* d_out, int out_size, void* d_ws, size_t ws_size,
                              hipStream_t stream)
{
    const float* x  = (const float*)d_in[0];
    const float* gw = (const float*)d_in[1];
    const float* w1 = (const float*)d_in[2];
    const float* w3 = (const float*)d_in[3];
    const float* w2 = (const float*)d_in[4];
    float* out = (float*)d_out;

    char* ws = (char*)d_ws;
    size_t off = 0;
    auto bump = [&](size_t bytes) -> void* {
        void* p = ws + off;
        off = (off + bytes + 255) & ~(size_t)255;
        return p;
    };
    int*   counts     = (int*)bump(32);
    int*   cursors    = (int*)bump(32);
    int*   offp       = (int*)bump(64);
    int*   topk_idx   = (int*)bump((size_t)PAIRS * 4);
    float* topk_w     = (float*)bump((size_t)PAIRS * 4);
    int*   pair_token = (int*)bump((size_t)PAD_MAX * 4);
    float* pair_w     = (float*)bump((size_t)PAD_MAX * 4);
    unsigned short* xb  = (unsigned short*)bump((size_t)T_TOKENS * HID * 2);
    unsigned short* w1b = (unsigned short*)bump((size_t)NEXP * INTER * HID * 2);
    unsigned short* w3b = (unsigned short*)bump((size_t)NEXP * INTER * HID * 2);
    unsigned short* w2b = (unsigned short*)bump((size_t)NEXP * HID * INTER * 2);
    unsigned short* act = (unsigned short*)(ws + off);

    size_t rem = (ws_size > off) ? (ws_size - off) : 0;
    int RC = (int)(rem / ((size_t)INTER * 2));
    RC &= ~255;
    if (RC > PAD_MAX) RC = PAD_MAX;
    if (RC < 256) RC = 256;
    int nchunks = (PAD_MAX + RC - 1) / RC;

    hipMemsetAsync(d_out, 0, (size_t)T_TOKENS * HID * 4, stream);
    hipMemsetAsync(ws, 0, 1024, stream);

    conv3_kernel<<<dim3(768, 3), 256, 0, stream>>>(w1, w3, w2, w1b, w3b, w2b);

    router_kernel<<<T_TOKENS/4, 256, 0, stream>>>(x, gw, topk_idx, topk_w, xb);
    hist_kernel<<<64, 256, 0, stream>>>(topk_idx, counts);
    scan_kernel<<<1, 64, 0, stream>>>(counts, offp);
    padfill_kernel<<<NEXP, 128, 0, stream>>>(counts, offp, pair_token, pair_w);
    scatter_kernel<<<T_TOKENS/256, 256, 0, stream>>>(topk_idx, topk_w, offp, cursors,
                                                     pair_token, pair_w);

    for (int c = 0; c < nchunks; ++c){
        int r0 = c * RC;
        gemm_act_kernel<<<dim3(INTER/128, RC/256), 512, 0, stream>>>(
            xb, w1b, w3b, offp, pair_token, pair_w, act, r0);
        gemm2_kernel<<<dim3(HID/128, RC/128), 256, 0, stream>>>(
            act, w2b, offp, pair_token, out, r0);
    }
}